// Round 9
// baseline (819.644 us; speedup 1.0000x reference)
//
#include <hip/hip_runtime.h>
#include <stdint.h>

#define DIMM 1024
#define NSEQ 1024
#define BB 2
#define HEADSN 16
#define MLPD 4096
#define DEPTHN 4
#define MROWS (BB*NSEQ)  // 2048
#define VSTR 10240       // canonical per-layer vec stride (elements)

typedef __bf16 bf16x8 __attribute__((ext_vector_type(8)));
typedef float f32x4 __attribute__((ext_vector_type(4)));
typedef unsigned short u16x8 __attribute__((ext_vector_type(8)));

__device__ __forceinline__ float bf2f(unsigned short u) {
    union { uint32_t i; float f; } x; x.i = ((uint32_t)u) << 16; return x.f;
}
__device__ __forceinline__ unsigned short f2bf(float f) {
    union { uint32_t i; float f; } x; x.f = f;
    uint32_t r = x.i + 0x7fffu + ((x.i >> 16) & 1u);
    return (unsigned short)(r >> 16);
}
__device__ __forceinline__ float loadf(const void* p, size_t i, int f32) {
    return f32 ? ((const float*)p)[i] : bf2f(((const unsigned short*)p)[i]);
}
// packed f32x2 -> bf16x2 (RNE), single HW instruction on gfx950
__device__ __forceinline__ uint32_t cvt_pk_bf16(float lo, float hi) {
    uint32_t r;
    asm("v_cvt_pk_bf16_f32 %0, %1, %2" : "=v"(r) : "v"(lo), "v"(hi));
    return r;
}

// async global->LDS, 16B per lane; LDS dest = wave-uniform base + lane*16
__device__ __forceinline__ void gl_lds16(const unsigned short* g, unsigned short* l) {
    __builtin_amdgcn_global_load_lds(
        (const __attribute__((address_space(1))) uint32_t*)g,
        (__attribute__((address_space(3))) uint32_t*)l,
        16, 0, 0);
}

// counted vmcnt waits (keep next-tile loads in flight across barriers)
__device__ __forceinline__ void wait_vm8() { asm volatile("s_waitcnt vmcnt(8)" ::: "memory"); }
__device__ __forceinline__ void wait_vm0() { asm volatile("s_waitcnt vmcnt(0)" ::: "memory"); }
// raw barrier fenced so the compiler can't move LDS ops across it
__device__ __forceinline__ void barrier_sync() {
    asm volatile("" ::: "memory");
    __builtin_amdgcn_s_barrier();
    asm volatile("" ::: "memory");
}

// ---------------- dtype sniff ----------------
__global__ __launch_bounds__(256) void sniff_kernel(const unsigned short* __restrict__ x,
                                                    int* __restrict__ flag) {
    __shared__ int cnt[256];
    int tid = threadIdx.x;
    int c = 0;
    for (int i = tid * 2; i < 65536; i += 512) {
        int e = (x[i] >> 7) & 0xFF;
        if (e >= 0x8A) c++;
    }
    cnt[tid] = c;
    __syncthreads();
    for (int s = 128; s > 0; s >>= 1) {
        if (tid < s) cnt[tid] += cnt[tid + s];
        __syncthreads();
    }
    if (tid == 0) flag[0] = (cnt[0] > 32) ? 1 : 0;
}

// ---------------- converts ----------------
__global__ __launch_bounds__(256) void store_out(const float* __restrict__ xf, void* __restrict__ out,
                                                 const int* __restrict__ flag) {
    int f = flag[0];
    int i = blockIdx.x * 256 + threadIdx.x;
    float v = xf[i];
    if (f) ((float*)out)[i] = v;
    else   ((unsigned short*)out)[i] = f2bf(v);
}
// all 7 small vectors in one launch; grid (64, 7)
__global__ __launch_bounds__(256) void conv_all(const void* s0, const void* s1, const void* s2,
                                                const void* s3, const void* s4, const void* s5,
                                                const void* s6, unsigned short* __restrict__ dst,
                                                const int* __restrict__ flag) {
    int f = flag[0];
    const void* src; int len, off;
    switch (blockIdx.y) {
        case 0: src = s0; len = 1024; off = 0;    break;
        case 1: src = s1; len = 1024; off = 1024; break;
        case 2: src = s2; len = 1024; off = 2048; break;
        case 3: src = s3; len = 1024; off = 3072; break;
        case 4: src = s4; len = 1024; off = 4096; break;
        case 5: src = s5; len = 1024; off = 5120; break;
        default: src = s6; len = 4096; off = 6144; break;
    }
    int i = blockIdx.x * 256 + threadIdx.x;
    if (i < DEPTHN * len) {
        int l = i / len, o = i - l * len;
        dst[l * VSTR + off + o] = f2bf(loadf(src, i, f));
    }
}

// ---------------- transpose+convert (scalar fallback) ----------------
__global__ __launch_bounds__(256) void transpose_conv(const void* __restrict__ in, size_t srcOffE,
                                                      unsigned short* __restrict__ out,
                                                      int K, int N, const int* __restrict__ flag) {
    int f = flag[0];
    __shared__ unsigned short t[32][33];
    int n0 = blockIdx.x * 32, k0 = blockIdx.y * 32;
    int tx = threadIdx.x, ty = threadIdx.y;  // 32 x 8
#pragma unroll
    for (int i = 0; i < 4; i++) {
        int k = k0 + ty + i * 8;
        t[ty + i * 8][tx] = f2bf(loadf(in, srcOffE + (size_t)k * N + n0 + tx, f));
    }
    __syncthreads();
#pragma unroll
    for (int i = 0; i < 4; i++) {
        int n = n0 + ty + i * 8;
        out[(size_t)n * K + k0 + tx] = t[tx][ty + i * 8];
    }
}

// ---------------- batched attn-half transpose (scalar fallback path) ----------------
__global__ __launch_bounds__(256) void transpose_attn(const void* __restrict__ qkvw,
                                                      const void* __restrict__ outw,
                                                      int layer, unsigned short* __restrict__ wT,
                                                      const int* __restrict__ flag) {
    int f = flag[0];
    __shared__ unsigned short t[32][33];
    int id = blockIdx.x;
    const void* src; int N; size_t soff; unsigned short* dst; int bx, by;
    if (id < 3072) {
        N = 3072; bx = id % 96; by = id / 96;
        src = qkvw; soff = (size_t)layer * 1024 * 3072; dst = wT;
    } else {
        id -= 3072; N = 1024; bx = id % 32; by = id / 32;
        src = outw; soff = (size_t)layer * 1024 * 1024; dst = wT + 3 * 1024 * 1024;
    }
    int n0 = bx * 32, k0 = by * 32;
    int tx = threadIdx.x, ty = threadIdx.y;  // 32 x 8
#pragma unroll
    for (int i = 0; i < 4; i++) {
        int k = k0 + ty + i * 8;
        t[ty + i * 8][tx] = f2bf(loadf(src, soff + (size_t)k * N + n0 + tx, f));
    }
    __syncthreads();
#pragma unroll
    for (int i = 0; i < 4; i++) {
        int n = n0 + ty + i * 8;
        dst[(size_t)n * 1024 + k0 + tx] = t[tx][ty + i * 8];
    }
}

// ---------------- V^T from V-part of qkv (fallback path only) ----------------
__global__ __launch_bounds__(256) void vt_kernel(const unsigned short* __restrict__ qkv,
                                                 unsigned short* __restrict__ vt) {
    __shared__ unsigned short t[64 * 70];
    int b = blockIdx.z;
    int c0 = blockIdx.x * 64, k0 = blockIdx.y * 64;
    int tid = threadIdx.x;
    int tx = tid & 15, ty = tid >> 4;  // 16 x 16
#pragma unroll
    for (int i = 0; i < 4; i++) {
        int r = ty + i * 16;
        uint2 v = *(const uint2*)&qkv[(size_t)(b * 1024 + k0 + r) * 3072 + 2048 + c0 + tx * 4];
        *(uint32_t*)&t[r * 70 + tx * 4]     = v.x;
        *(uint32_t*)&t[r * 70 + tx * 4 + 2] = v.y;
    }
    __syncthreads();
#pragma unroll
    for (int i = 0; i < 4; i++) {
        int c = ty + i * 16;
        ushort4 o;
        o.x = t[(tx * 4 + 0) * 70 + c];
        o.y = t[(tx * 4 + 1) * 70 + c];
        o.z = t[(tx * 4 + 2) * 70 + c];
        o.w = t[(tx * 4 + 3) * 70 + c];
        *(ushort4*)&vt[(size_t)(b * 1024 + c0 + c) * 1024 + k0 + tx * 4] = o;
    }
}

// ---------------- ALL weight transposes, vectorized 64x64 tiles, u16x8 stores ----------------
__global__ __launch_bounds__(256) void transpose_all(const void* __restrict__ qkvw,
                                                     const void* __restrict__ outw,
                                                     const void* __restrict__ ff1w,
                                                     const void* __restrict__ ff2w,
                                                     unsigned short* __restrict__ wTall,
                                                     const int* __restrict__ flag) {
    int f = flag[0];
    __shared__ unsigned short t[64 * 70];
    int id = blockIdx.x;
    int l = blockIdx.y;
    unsigned short* base = wTall + (size_t)l * (12u * 1024 * 1024);
    const void* src; int K, N; size_t soff; unsigned short* dst;
    if (id < 768)       { src = qkvw; K = 1024; N = 3072; soff = (size_t)l * 1024 * 3072; dst = base; }
    else if (id < 1024) { id -= 768;  src = outw; K = 1024; N = 1024; soff = (size_t)l * 1024 * 1024; dst = base + 3 * 1024 * 1024; }
    else if (id < 2048) { id -= 1024; src = ff1w; K = 1024; N = 4096; soff = (size_t)l * 1024 * 4096; dst = base + 4 * 1024 * 1024; }
    else                { id -= 2048; src = ff2w; K = 4096; N = 1024; soff = (size_t)l * 4096 * 1024; dst = base + 8 * 1024 * 1024; }
    int nb = N >> 6;
    int by = id / nb, bx = id - by * nb;
    int n0 = bx * 64, k0 = by * 64;
    int tid = threadIdx.x;
    int tx = tid & 15, ty = tid >> 4;  // 16 x 16
#pragma unroll
    for (int i = 0; i < 4; i++) {
        int r = ty + i * 16;
        size_t s = soff + (size_t)(k0 + r) * N + n0 + tx * 4;
        uint32_t w0, w1;
        if (f) {
            float4 v = *(const float4*)((const float*)src + s);
            w0 = cvt_pk_bf16(v.x, v.y);
            w1 = cvt_pk_bf16(v.z, v.w);
        } else {
            uint2 v = *(const uint2*)((const unsigned short*)src + s);
            w0 = v.x; w1 = v.y;
        }
        *(uint32_t*)&t[r * 70 + tx * 4]     = w0;
        *(uint32_t*)&t[r * 70 + tx * 4 + 2] = w1;
    }
    __syncthreads();
    int tx2 = tid & 7, ty2 = tid >> 3;  // 8 x 32
#pragma unroll
    for (int i = 0; i < 2; i++) {
        int n = ty2 + i * 32;
        u16x8 o;
#pragma unroll
        for (int j = 0; j < 8; j++) o[j] = t[(tx2 * 8 + j) * 70 + n];
        *(u16x8*)&dst[(size_t)(n0 + n) * K + k0 + tx2 * 8] = o;
    }
}

// ---------------- mask -> bitmask u64 words ----------------
__global__ __launch_bounds__(256) void mask_pack(const int* __restrict__ mask,
                                                 unsigned long long* __restrict__ bits) {
    int wid = (blockIdx.x * 256 + threadIdx.x) >> 6;
    int lane = threadIdx.x & 63;
#pragma unroll
    for (int i = 0; i < 16; i++) {
        int w = wid * 16 + i;
        int mv = mask[(size_t)w * 64 + lane];
        unsigned long long bl = __ballot(mv != 0);
        if (lane == 0) bits[w] = bl;
    }
}

// ---------------- fused cvt + LayerNorm from raw x (first pre-attn LN) ----------------
__global__ __launch_bounds__(256) void ln_raw(const void* __restrict__ x, float* __restrict__ xf,
                                              const unsigned short* __restrict__ g,
                                              const unsigned short* __restrict__ bta,
                                              unsigned short* __restrict__ out,
                                              const int* __restrict__ flag) {
    int f = flag[0];
    int row = blockIdx.x, tid = threadIdx.x;
    size_t base = (size_t)row * DIMM;
    float v[4]; float s = 0.f, s2 = 0.f;
#pragma unroll
    for (int i = 0; i < 4; i++) {
        int c = tid + i * 256;
        v[i] = loadf(x, base + c, f);
        xf[base + c] = v[i];
        s += v[i]; s2 += v[i] * v[i];
    }
#pragma unroll
    for (int off = 32; off >= 1; off >>= 1) {
        s  += __shfl_down(s, off, 64);
        s2 += __shfl_down(s2, off, 64);
    }
    __shared__ float rs[4], rs2[4];
    int wv = tid >> 6;
    if ((tid & 63) == 0) { rs[wv] = s; rs2[wv] = s2; }
    __syncthreads();
    s  = rs[0] + rs[1] + rs[2] + rs[3];
    s2 = rs2[0] + rs2[1] + rs2[2] + rs2[3];
    float mu  = s * (1.f / DIMM);
    float var = s2 * (1.f / DIMM) - mu * mu;
    float rr  = rsqrtf(var + 1e-5f);
#pragma unroll
    for (int i = 0; i < 4; i++) {
        int c = tid + i * 256;
        float y = (v[i] - mu) * rr * bf2f(g[c]) + bf2f(bta[c]);
        out[base + c] = f2bf(y);
    }
}

// ---------------- LayerNorm (standalone fallback) ----------------
__global__ __launch_bounds__(256) void ln_kernel(const float* __restrict__ x,
                                                 const unsigned short* __restrict__ g,
                                                 const unsigned short* __restrict__ bta,
                                                 unsigned short* __restrict__ out) {
    int row = blockIdx.x, tid = threadIdx.x;
    const float* xr = x + (size_t)row * DIMM;
    float v[4]; float s = 0.f, s2 = 0.f;
#pragma unroll
    for (int i = 0; i < 4; i++) { v[i] = xr[tid + i * 256]; s += v[i]; s2 += v[i] * v[i]; }
#pragma unroll
    for (int off = 32; off >= 1; off >>= 1) {
        s  += __shfl_down(s, off, 64);
        s2 += __shfl_down(s2, off, 64);
    }
    __shared__ float rs[4], rs2[4];
    int wv = tid >> 6;
    if ((tid & 63) == 0) { rs[wv] = s; rs2[wv] = s2; }
    __syncthreads();
    s  = rs[0] + rs[1] + rs[2] + rs[3];
    s2 = rs2[0] + rs2[1] + rs2[2] + rs2[3];
    float mu  = s * (1.f / DIMM);
    float var = s2 * (1.f / DIMM) - mu * mu;
    float rr  = rsqrtf(var + 1e-5f);
#pragma unroll
    for (int i = 0; i < 4; i++) {
        int c = tid + i * 256;
        float y = (v[i] - mu) * rr * bf2f(g[c]) + bf2f(bta[c]);
        out[(size_t)row * DIMM + c] = f2bf(y);
    }
}

// ---------------- split-K slab reduce + residual update (+ optional fused LN) ----------------
template <int S, int HAS_LN>
__global__ __launch_bounds__(256) void reduce_ln(const float* __restrict__ slab,
                                                 const unsigned short* __restrict__ bias,
                                                 float* __restrict__ xf,
                                                 const unsigned short* __restrict__ g,
                                                 const unsigned short* __restrict__ bta,
                                                 unsigned short* __restrict__ out) {
    const size_t SL = (size_t)MROWS * DIMM;
    int row = blockIdx.x, tid = threadIdx.x;
    float v[4]; float s = 0.f, s2 = 0.f;
#pragma unroll
    for (int i = 0; i < 4; i++) {
        int c = tid + i * 256;
        size_t idx = (size_t)row * DIMM + c;
        float t = xf[idx] + bf2f(bias[c]);
#pragma unroll
        for (int z = 0; z < S; z++) t += slab[z * SL + idx];
        xf[idx] = t;
        v[i] = t; s += t; s2 += t * t;
    }
    if (HAS_LN) {
#pragma unroll
        for (int off = 32; off >= 1; off >>= 1) {
            s  += __shfl_down(s, off, 64);
            s2 += __shfl_down(s2, off, 64);
        }
        __shared__ float rs[4], rs2[4];
        int wv = tid >> 6;
        if ((tid & 63) == 0) { rs[wv] = s; rs2[wv] = s2; }
        __syncthreads();
        s  = rs[0] + rs[1] + rs[2] + rs[3];
        s2 = rs2[0] + rs2[1] + rs2[2] + rs2[3];
        float mu  = s * (1.f / DIMM);
        float var = s2 * (1.f / DIMM) - mu * mu;
        float rr  = rsqrtf(var + 1e-5f);
#pragma unroll
        for (int i = 0; i < 4; i++) {
            int c = tid + i * 256;
            float y = (v[i] - mu) * rr * bf2f(g[c]) + bf2f(bta[c]);
            out[(size_t)row * DIMM + c] = f2bf(y);
        }
    }
}

// ---------------- GEMM (m97 geometry: 4 waves x 64x64 wave-tile, 128x128 block,
//                        BK=64, dbuf + counted vmcnt(8)) ----------------
// 256 threads = 4 waves; wave-tile 64x64 (wm=(w>>1)*64, wn=(w&1)*64); acc[4][4].
// Per K-step per wave: 8x gl_lds16 stage (4 A-chunks + 4 B-chunks of 8 rows each),
// 16 ds_read_b128, 32 MFMA -> ~2x operand reuse per LDS read vs the old 8-wave 64x32
// layout (which was LDS-read-bound).  Granule swizzle g' = g ^ (row&7) unchanged
// (all row-block offsets are multiples of 8 so the read-side XOR formula still holds).
// Double-buffered with counted vmcnt(8): stage(t+1)'s 8 loads stay in flight.
// MODE 0: store bf16 C (VtOut: fused V^T epilogue for nBase>=2048)
// MODE 1: Cres atomic += (fallback)  MODE 2: bf16 gelu(acc+bias)  MODE 3: slab[z]=acc
template <int MODE, int SPLITK>
__global__ __launch_bounds__(256) void gemm_bt(const unsigned short* __restrict__ A,
                                               const unsigned short* __restrict__ Bt,
                                               const unsigned short* __restrict__ bias,
                                               unsigned short* __restrict__ Cbf,
                                               float* __restrict__ Cres,
                                               unsigned short* __restrict__ VtOut,
                                               int M, int N, int K) {
    __shared__ __align__(16) unsigned short LDSbuf[4 * 128 * 64];
    unsigned short* As0 = LDSbuf;
    unsigned short* Bs0 = LDSbuf + 8192;
    unsigned short* As1 = LDSbuf + 16384;
    unsigned short* Bs1 = LDSbuf + 24576;
    const int tid = threadIdx.x;
    const int mBase = blockIdx.y * 128, nBase = blockIdx.x * 128;
    const int w = tid >> 6, lane = tid & 63;
    const int wm = (w >> 1) * 64, wn = (w & 1) * 64;
    const int quad = lane >> 4, l16 = lane & 15;
    const int kLen = K / SPLITK;
    const int kStart = (SPLITK > 1) ? blockIdx.z * kLen : 0;
    const int NT = kLen / 64;  // 8/16 here, always even

    f32x4 acc[4][4];
#pragma unroll
    for (int i = 0; i < 4; i++)
#pragma unroll
        for (int j = 0; j < 4; j++) acc[i][j] = (f32x4){0.f, 0.f, 0.f, 0.f};

    // staging: wave w stages A rows [w*32, w*32+32) and B rows [w*32, w*32+32);
    // each gl_lds16 covers 8 rows x 8 granules; source granule pre-swizzled by row&7.
    const int lr8 = lane >> 3;
    const int sgran = (lane & 7) ^ lr8;
    const unsigned short* GA = A  + (size_t)(mBase + w * 32 + lr8) * K + kStart + sgran * 8;
    const unsigned short* GB = Bt + (size_t)(nBase + w * 32 + lr8) * K + kStart + sgran * 8;
    unsigned short* SA0 = As0 + (w * 32) * 64;
    unsigned short* SB0 = Bs0 + (w * 32) * 64;
    unsigned short* SA1 = As1 + (w * 32) * 64;
    unsigned short* SB1 = Bs1 + (w * 32) * 64;
    const size_t r8 = (size_t)8 * K;

    const int rg0 = (quad ^ (l16 & 7)) * 8;
    const int rg1 = ((4 + quad) ^ (l16 & 7)) * 8;

    auto stage = [&](unsigned short* SA, unsigned short* SB, int t) {
        const unsigned short* ga = GA + (size_t)t * 64;
        const unsigned short* gb = GB + (size_t)t * 64;
#pragma unroll
        for (int i = 0; i < 4; i++) {
            gl_lds16(ga + (size_t)i * r8, SA + i * 8 * 64);
            gl_lds16(gb + (size_t)i * r8, SB + i * 8 * 64);
        }
    };
    auto compute = [&](const unsigned short* Asb, const unsigned short* Bsb) {
#pragma unroll
        for (int ks = 0; ks < 2; ks++) {
            const int rg = ks ? rg1 : rg0;
            bf16x8 af[4], bfv[4];
#pragma unroll
            for (int i = 0; i < 4; i++)
                af[i] = *(const bf16x8*)&Asb[(wm + i * 16 + l16) * 64 + rg];
#pragma unroll
            for (int j = 0; j < 4; j++)
                bfv[j] = *(const bf16x8*)&Bsb[(wn + j * 16 + l16) * 64 + rg];
#pragma unroll
            for (int i = 0; i < 4; i++)
#pragma unroll
                for (int j = 0; j < 4; j++)
                    acc[i][j] = __builtin_amdgcn_mfma_f32_16x16x32_bf16(af[i], bfv[j], acc[i][j], 0, 0, 0);
        }
    };

    stage(SA0, SB0, 0);
    for (int t = 0; t < NT; t += 2) {
        stage(SA1, SB1, t + 1);
        wait_vm8();       // my tile-t loads landed (8 newest = tile t+1, in flight)
        barrier_sync();
        compute(As0, Bs0);
        barrier_sync();
        if (t + 2 < NT) {
            stage(SA0, SB0, t + 2);
            wait_vm8();
        } else {
            wait_vm0();
        }
        barrier_sync();
        compute(As1, Bs1);
        barrier_sync();
    }

    // fused V^T epilogue (qkv GEMM, V third) — whole block takes this path uniformly
    if (MODE == 0 && VtOut != nullptr && nBase >= 2048) {
        unsigned short* T = LDSbuf;  // 128 x 136 u16 = 34816 B <= 64 KB
#pragma unroll
        for (int i = 0; i < 4; i++)
#pragma unroll
            for (int j = 0; j < 4; j++)
#pragma unroll
                for (int r = 0; r < 4; r++)
                    T[(wn + j * 16 + l16) * 136 + (wm + i * 16 + quad * 4 + r)] =
                        f2bf(acc[i][j][r]);
        barrier_sync();
        const int b = mBase >> 10, kk = mBase & 1023;
        const int tx = tid & 15, ty = tid >> 4;  // 16 x 16
#pragma unroll
        for (int p = 0; p < 8; p++) {
            int c = ty + p * 16;
            u16x8 val = *(const u16x8*)&T[c * 136 + tx * 8];
            *(u16x8*)&VtOut[(size_t)(b * 1024 + (nBase - 2048) + c) * 1024 + kk + tx * 8] = val;
        }
        return;
    }

    const size_t slabOff = (MODE == 3) ? (size_t)blockIdx.z * M * N : 0;
#pragma unroll
    for (int i = 0; i < 4; i++) {
#pragma unroll
        for (int j = 0; j < 4; j++) {
#pragma unroll
            for (int r = 0; r < 4; r++) {
                int m = mBase + wm + i * 16 + quad * 4 + r;
                int n = nBase + wn + j * 16 + l16;
                float v = acc[i][j][r];
                size_t idx = (size_t)m * N + n;
                if (MODE == 0) {
                    Cbf[idx] = f2bf(v);
                } else if (MODE == 1) {
                    if (SPLITK > 1) {
                        if (blockIdx.z == 0) v += bf2f(bias[n]);
                        atomicAdd(&Cres[idx], v);
                    } else {
                        Cres[idx] += v + bf2f(bias[n]);
                    }
                } else if (MODE == 2) {
                    float t2 = v + bf2f(bias[n]);
                    float gg = 0.5f * t2 * (1.f + erff(t2 * 0.70710678118f));
                    Cbf[idx] = f2bf(gg);
                } else {
                    Cres[slabOff + idx] = v;
                }
            }
        }
    }
}

// ---------------- MFMA flash attention (swapped-QK, in-register P, dbuf K/V pipeline) ----------------
__global__ __launch_bounds__(256) void attn_mfma(const unsigned short* __restrict__ qkv,
                                                 const unsigned short* __restrict__ vt,
                                                 const unsigned long long* __restrict__ mbits,
                                                 unsigned short* __restrict__ o) {
    __shared__ __align__(16) unsigned short Ks[2][64 * 72];
    __shared__ __align__(16) unsigned short Vs[2][64 * 72];

    const int tid = threadIdx.x, w = tid >> 6, lane = tid & 63;
    const int quad = lane >> 4, l16 = lane & 15;
    const int qt = blockIdx.x, h = blockIdx.y, b = blockIdx.z;

    const size_t qrow = (size_t)(b * NSEQ + qt * 64 + w * 16 + l16) * 3072 + h * 64;
    bf16x8 qf[2];
    qf[0] = *(const bf16x8*)(qkv + qrow + quad * 8);
    qf[1] = *(const bf16x8*)(qkv + qrow + 32 + quad * 8);

    const int srow = tid >> 2, scol = (tid & 3) * 16;
    const unsigned short* kg0 = qkv + (size_t)(b * NSEQ) * 3072 + 1024 + h * 64
                                + (size_t)srow * 3072 + scol;
    const unsigned short* vg0 = vt + (size_t)((b * HEADSN + h) * 64 + srow) * 1024 + scol;

    f32x4 oacc[4];
#pragma unroll
    for (int j = 0; j < 4; j++) oacc[j] = (f32x4){0.f, 0.f, 0.f, 0.f};
    float m_run = -1e30f, l_run = 0.f;

    const unsigned long long* mb = mbits + ((size_t)(b * NSEQ + qt * 64 + w * 16 + l16)) * 16;

    // prologue: stage kt=0 into buf 0
    uint4 ka = *(const uint4*)kg0;
    uint4 kb = *(const uint4*)(kg0 + 8);
    uint4 va = *(const uint4*)vg0;
    uint4 vb = *(const uint4*)(vg0 + 8);
    *(uint4*)&Ks[0][srow * 72 + scol]     = ka;
    *(uint4*)&Ks[0][srow * 72 + scol + 8] = kb;
    *(uint4*)&Vs[0][srow * 72 + scol]     = va;
    *(uint4*)&Vs[0][srow * 72 + scol + 8] = vb;
    unsigned long long mw = mb[0];
    int cur = 0;

    for (int kt = 0; kt < 16; kt++) {
        __syncthreads();  // buf[cur] writes visible; prior iter's reads of buf[cur^1] done

        unsigned long long mw_n = 0;
        if (kt < 15) {  // issue kt+1 loads now; consumed (LDS-written) after compute
            const unsigned short* kg = kg0 + (size_t)(kt + 1) * 64 * 3072;
            ka = *(const uint4*)kg;
            kb = *(const uint4*)(kg + 8);
            const unsigned short* vg = vg0 + (kt + 1) * 64;
            va = *(const uint4*)vg;
            vb = *(const uint4*)(vg + 8);
            mw_n = mb[kt + 1];
        }

        // S^T: sacc[j][r] = S[q=l16][k = j*16 + quad*4 + r]
        f32x4 sacc[4];
#pragma unroll
        for (int j = 0; j < 4; j++) sacc[j] = (f32x4){0.f, 0.f, 0.f, 0.f};
        __builtin_amdgcn_s_setprio(1);
#pragma unroll
        for (int ks = 0; ks < 2; ks++) {
#pragma unroll
            for (int j = 0; j < 4; j++) {
                bf16x8 kf = *(const bf16x8*)&Ks[cur][(j * 16 + l16) * 72 + ks * 32 + quad * 8];
                sacc[j] = __builtin_amdgcn_mfma_f32_16x16x32_bf16(kf, qf[ks], sacc[j], 0, 0, 0);
            }
        }
        __builtin_amdgcn_s_setprio(0);

        float t[4][4];
        float mxj[4];
#pragma unroll
        for (int j = 0; j < 4; j++) {
            unsigned nib = (unsigned)(mw >> (quad * 4 + j * 16)) & 0xFu;
#pragma unroll
            for (int r = 0; r < 4; r++) {
                float s = sacc[j][r] * 0.125f;
                t[j][r] = ((nib >> r) & 1u) ? s : -1e30f;
            }
            mxj[j] = fmaxf(fmaxf(t[j][0], t[j][1]), fmaxf(t[j][2], t[j][3]));
        }
        float mx = fmaxf(fmaxf(mxj[0], mxj[1]), fmaxf(mxj[2], mxj[3]));
        mx = fmaxf(mx, __shfl_xor(mx, 16, 64));
        mx = fmaxf(mx, __shfl_xor(mx, 32, 64));

        if (!__all(mx <= m_run)) {
            float m_new = fmaxf(m_run, mx);
            float alpha = __expf(m_run - m_new);
            m_run = m_new;
            l_run *= alpha;
            float al[4];
#pragma unroll
            for (int r = 0; r < 4; r++) al[r] = __shfl(alpha, quad * 4 + r, 64);
#pragma unroll
            for (int j = 0; j < 4; j++)
#pragma unroll
                for (int r = 0; r < 4; r++) oacc[j][r] *= al[r];
        }

        float p[4][4];
        float psj[4];
#pragma unroll
        for (int j = 0; j < 4; j++) {
#pragma unroll
            for (int r = 0; r < 4; r++) p[j][r] = __expf(t[j][r] - m_run);
            psj[j] = (p[j][0] + p[j][1]) + (p[j][2] + p[j][3]);
        }
        float ps = (psj[0] + psj[1]) + (psj[2] + psj[3]);
        ps += __shfl_xor(ps, 16, 64);
        ps += __shfl_xor(ps, 32, 64);
        l_run += ps;

        union { uint32_t u[4]; bf16x8 v; } pa[2];
#pragma unroll
        for (int ks = 0; ks < 2; ks++) {
            pa[ks].u[0] = cvt_pk_bf16(p[2 * ks][0],     p[2 * ks][1]);
            pa[ks].u[1] = cvt_pk_bf16(p[2 * ks][2],     p[2 * ks][3]);
            pa[ks].u[2] = cvt_pk_bf16(p[2 * ks + 1][0], p[2 * ks + 1][1]);
            pa[ks].u[3] = cvt_pk_bf16(p[2 * ks + 1][2], p[2 * ks + 1][3]);
        }

        __builtin_amdgcn_s_setprio(1);
#pragma unroll
        for (int ks = 0; ks < 2; ks++) {
#pragma unroll
            for (int j = 0; j < 4; j++) {
                union { ushort4 u[2]; bf16x8 v; } vf;
                const unsigned short* vp = &Vs[cur][(j * 16 + l16) * 72 + ks * 32 + quad * 4];
                vf.u[0] = *(const ushort4*)vp;
                vf.u[1] = *(const ushort4*)(vp + 16);
                oacc[j] = __builtin_amdgcn_mfma_f32_16x16x32_bf16(pa[ks].v, vf.v, oacc[j], 0, 0, 0);
            }
        }
        __builtin_amdgcn_s_setprio(0);

        if (kt < 15) {  // write-late: land kt+1 into the other buffer
            *(uint4*)&Ks[cur ^ 1][srow * 72 + scol]     = ka;
            *(uint4*)&Ks[cur ^ 1][srow * 72 + scol + 8] = kb;
            *(uint4*)&Vs[cur ^ 1][srow * 72 + scol]     = va;
            *(uint4*)&Vs[cur ^ 1][srow * 72 + scol + 8] = vb;
            mw = mw_n;
            cur ^= 1;
        }
    }

    float inv[4];
#pragma unroll
    for (int r = 0; r < 4; r++) {
        float lr = __shfl(l_run, quad * 4 + r, 64);
        inv[r] = 1.f / lr;
    }
#pragma unroll
    for (int j = 0; j < 4; j++) {
#pragma unroll
        for (int r = 0; r < 4; r++) {
            size_t row = (size_t)(b * NSEQ + qt * 64 + w * 16 + quad * 4 + r);
            o[row * 1024 + h * 64 + j * 16 + l16] = f2bf(oacc[j][r] * inv[r]);
        }
    }
}

extern "C" void kernel_launch(void* const* d_in, const int* in_sizes, int n_in,
                              void* d_out, int out_size, void* d_ws, size_t ws_size,
                              hipStream_t stream) {
    const void* x     = d_in[0];
    const int*  mask  = (const int*)d_in[1];
    const void* ln1_g = d_in[2];
    const void* ln1_b = d_in[3];
    const void* qkv_w = d_in[4];
    const void* out_w = d_in[5];
    const void* out_b = d_in[6];
    const void* ln2_g = d_in[7];
    const void* ln2_b = d_in[8];
    const void* ff1_w = d_in[9];
    const void* ff1_b = d_in[10];
    const void* ff2_w = d_in[11];
    const void* ff2_b = d_in[12];

    char* ws = (char*)d_ws;
    float*          xf     = (float*)ws;                            // 8 MB fp32 residual
    unsigned short* h_bf   = (unsigned short*)(ws + (8u  << 20));   // 4 MB LN out
    unsigned short* qkv_bf = (unsigned short*)(ws + (12u << 20));   // 12 MB (attn half)
    unsigned short* ff_bf  = (unsigned short*)(ws + (12u << 20));   // 16 MB (ff half)
    unsigned short* vt_bf  = (unsigned short*)(ws + (24u << 20));   // 4 MB V^T (attn half)
    unsigned short* o_bf   = (unsigned short*)(ws + (28u << 20));   // 4 MB
    unsigned short* wT     = (unsigned short*)(ws + (32u << 20));   // 8 MB transposed weight (fallback)
    unsigned short* vecs   = (unsigned short*)(ws + (40u << 20));   // 80 KB canonical vecs
    int*            flag   = (int*)(ws + (40u << 20) + (128u << 10));
    unsigned long long* mbits = (unsigned long long*)(ws + (40u << 20) + (192u << 10)); // 256 KB
    float*          slab   = (float*)(ws + (41u << 20));            // up to 32 MB split-K slabs
    unsigned short* wTall  = (unsigned short*)(ws + (73ull << 20)); // 96 MB all-layer weights

    const bool slabs_ok = ws_size >= (74ull << 20);
    const bool bigws    = ws_size >= (170ull << 20);

    sniff_kernel<<<1, 256, 0, stream>>>((const unsigned short*)x, flag);

    conv_all<<<dim3(64, 7), 256, 0, stream>>>(ln1_g, ln1_b, out_b, ln2_g, ln2_b, ff2_b, ff1_b,
                                              vecs, flag);
    mask_pack<<<512, 256, 0, stream>>>(mask, mbits);

    // fused cvt_x + first pre-attn LN (layer 0)
    ln_raw<<<MROWS, 256, 0, stream>>>(x, xf, vecs + 0, vecs + 1024, h_bf, flag);

    if (bigws)  // all 16 weight transposes in one vectorized launch
        transpose_all<<<dim3(3072, 4), 256, 0, stream>>>(
            qkv_w, out_w, ff1_w, ff2_w, wTall, flag);

    const int nx = MROWS * DIMM;  // 2M

    for (int l = 0; l < DEPTHN; l++) {
        const unsigned short* lv = vecs + l * VSTR;
        const unsigned short* lvn = vecs + (l + 1) * VSTR;  // next layer's vecs (l<3)

        const unsigned short* lbase = bigws ? wTall + (size_t)l * (12u * 1024 * 1024) : wT;
        const unsigned short* qkvT = lbase;
        const unsigned short* outT = lbase + 3 * 1024 * 1024;
        const unsigned short* ff1T = bigws ? lbase + 4 * 1024 * 1024 : wT;
        const unsigned short* ff2T = bigws ? lbase + 8 * 1024 * 1024 : wT;

        // --- attention half ---
        if (!bigws)
            transpose_attn<<<4096, dim3(32, 8), 0, stream>>>(qkv_w, out_w, l, wT, flag);
        // qkv GEMM with fused V^T epilogue (V-blocks write vt_bf directly)
        gemm_bt<0, 1><<<dim3(3072 / 128, MROWS / 128), 256, 0, stream>>>(
            h_bf, qkvT, nullptr, qkv_bf, nullptr, vt_bf, MROWS, 3072, 1024);
        attn_mfma<<<dim3(NSEQ / 64, HEADSN, BB), 256, 0, stream>>>(qkv_bf, vt_bf, mbits, o_bf);
        if (slabs_ok) {
            gemm_bt<3, 2><<<dim3(1024 / 128, MROWS / 128, 2), 256, 0, stream>>>(
                o_bf, outT, nullptr, nullptr, slab, nullptr, MROWS, 1024, 1024);
            reduce_ln<2, 1><<<MROWS, 256, 0, stream>>>(
                slab, lv + 2048, xf, lv + 3072, lv + 4096, h_bf);
        } else {
            gemm_bt<1, 2><<<dim3(1024 / 128, MROWS / 128, 2), 256, 0, stream>>>(
                o_bf, outT, lv + 2048, nullptr, xf, nullptr, MROWS, 1024, 1024);
            ln_kernel<<<MROWS, 256, 0, stream>>>(xf, lv + 3072, lv + 4096, h_bf);
        }

        // --- feedforward half ---
        if (!bigws)
            transpose_conv<<<dim3(4096 / 32, 1024 / 32), dim3(32, 8), 0, stream>>>(
                ff1_w, (size_t)l * 1024 * 4096, wT, 1024, 4096, flag);
        gemm_bt<2, 1><<<dim3(4096 / 128, MROWS / 128), 256, 0, stream>>>(
            h_bf, ff1T, lv + 6144, ff_bf, nullptr, nullptr, MROWS, 4096, 1024);
        if (!bigws)
            transpose_conv<<<dim3(1024 / 32, 4096 / 32), dim3(32, 8), 0, stream>>>(
                ff2_w, (size_t)l * 4096 * 1024, wT, 4096, 1024, flag);
        if (slabs_ok) {
            gemm_bt<3, 4><<<dim3(1024 / 128, MROWS / 128, 4), 256, 0, stream>>>(
                ff_bf, ff2T, nullptr, nullptr, slab, nullptr, MROWS, 1024, 4096);
            if (l < DEPTHN - 1)
                reduce_ln<4, 1><<<MROWS, 256, 0, stream>>>(
                    slab, lv + 5120, xf, lvn + 0, lvn + 1024, h_bf);
            else
                reduce_ln<4, 0><<<MROWS, 256, 0, stream>>>(
                    slab, lv + 5120, xf, nullptr, nullptr, nullptr);
        } else {
            gemm_bt<1, 4><<<dim3(1024 / 128, MROWS / 128, 4), 256, 0, stream>>>(
                ff_bf, ff2T, lv + 5120, nullptr, xf, nullptr, MROWS, 1024, 4096);
            if (l < DEPTHN - 1)
                ln_kernel<<<MROWS, 256, 0, stream>>>(xf, lvn + 0, lvn + 1024, h_bf);
        }
    }

    store_out<<<nx / 256, 256, 0, stream>>>(xf, d_out, flag);
}